// Round 1
// 3759.615 us; speedup vs baseline: 1.2652x; 1.2652x over previous
//
#include <hip/hip_runtime.h>

// EP free-phase relaxation — fp16 MFMA, 2-term activation split, deep-pipelined K-loop.
// B=256, D=4096, N=30, DT=0.5.
//   n0 = clip(0.5*c0 + 0.5*(r1@W0^T + b0))
//   n1 = clip(0.5*c1 + 0.5*(r2@W2^T + r0@W1^T + b2))   (K=8192 via 2 passes)
//   n2 = clip(0.5*c2 + 0.5*(top + r1@W3^T))            top = r3@W4^T + b4
// Numerics identical to prior version (absmax 7.8e-3): W fp16; activations split
// hi+lo fp16 into one fp32 MFMA accumulator, same accumulation order.
//
// New structure (this round): latency-bound fix.
//  - 512 uniform blocks: z0 128 wide (BN=256), z1 256 narrow (BN=128, 2 K-passes),
//    z2 128 wide. 2 blocks/CU (60KB LDS each), same-W blocks stride 16/32 -> same XCD.
//  - K-loop: BK=32, 3 rotating LDS buffers, prefetch depth 2, ONE raw s_barrier/iter,
//    counted s_waitcnt vmcnt(G) (G=5 wide / 3 narrow) — never vmcnt(0) in steady state.
//  - LDS bank-conflict fix: 16B chunk XOR-swizzle (chunk ^= (row>>1)&3), applied on
//    the per-lane GLOBAL source addr at stage time (gl_lds dest stays linear) and on
//    the ds_read offset.
//  - s_setprio(1) around MFMA cluster.

typedef unsigned short u16;
typedef __attribute__((ext_vector_type(8))) _Float16 f16x8;
typedef __attribute__((ext_vector_type(4))) float f32x4;

constexpr int Bb = 256, Dd = 4096, NSTEPS = 30;
constexpr long BD = (long)Bb * Dd;   // 1,048,576
constexpr long DD = (long)Dd * Dd;   // 16,777,216
constexpr int BM = 32;
constexpr int NBUF = 3;
constexpr int BUFB = 20480;          // per-buffer bytes: AsH 2K | AsL 2K | Ws 16K

__device__ inline u16 f2h(float f) { union { _Float16 h; u16 u; } v; v.h = (_Float16)f; return v.u; }
__device__ inline float h2f(u16 b) { union { u16 u; _Float16 h; } v; v.u = b; return (float)v.h; }

__device__ inline void gl_lds16(const u16* g, void* l) {
    __builtin_amdgcn_global_load_lds(
        (const __attribute__((address_space(1))) void*)g,
        (__attribute__((address_space(3))) void*)l, 16, 0, 0);
}

__global__ __launch_bounds__(256)
void convert_w(const float* __restrict__ src, u16* __restrict__ dst, long n) {
    long i = (long)blockIdx.x * blockDim.x + threadIdx.x;
    const long stride = (long)gridDim.x * blockDim.x;
    for (long v = i; v < (n >> 2); v += stride) {
        float4 x = ((const float4*)src)[v];
        ushort4 o; o.x = f2h(x.x); o.y = f2h(x.y); o.z = f2h(x.z); o.w = f2h(x.w);
        ((ushort4*)dst)[v] = o;
    }
}

__global__ __launch_bounds__(256)
void convert_s(const float* __restrict__ src, u16* __restrict__ hi, u16* __restrict__ lo, long n) {
    long i = (long)blockIdx.x * blockDim.x + threadIdx.x;
    const long stride = (long)gridDim.x * blockDim.x;
    for (long v = i; v < (n >> 2); v += stride) {
        float4 x = ((const float4*)src)[v];
        float a[4] = {x.x, x.y, x.z, x.w};
        ushort4 oh, ol;
        u16* ph = (u16*)&oh; u16* pl = (u16*)&ol;
        #pragma unroll
        for (int j = 0; j < 4; ++j) {
            float c = fminf(fmaxf(a[j], 0.f), 1.f);
            u16 hb = f2h(c);
            ph[j] = hb;
            pl[j] = f2h(c - h2f(hb));
        }
        ((ushort4*)hi)[v] = oh;
        ((ushort4*)lo)[v] = ol;
    }
}

// Stage one BK=32 K-tile into LDS buffer `buf`.
// Layout (per buffer): AsH [32 rows][32] @0 | AsL @2048 | Ws [BN rows][32] @4096.
// 64B rows, linear gl_lds dest (waveBase + lane*16); the 16B chunk within each row
// is XOR-swizzled via the GLOBAL source address: chunk_slot c holds global chunk
// c ^ ((row%16)>>1 & 3).
template<bool WIDE>
__device__ inline void stage_tile(const u16* aH, const u16* aL, const u16* W,
                                  int m0, int n0, int k, char* buf, int wv, int lane)
{
    const int srow = lane >> 2;                                  // row within 16-row wave chunk
    const int koff = (((lane & 3) ^ ((lane >> 3) & 3)) << 3);    // swizzled chunk, in elements
    // A: waves 0/1 stage hi rows [16w,16w+16); waves 2/3 stage lo.
    const u16* aBase = (wv < 2) ? aH : aL;
    const int aRow = ((wv & 1) << 4) + srow;
    char* aDst = buf + ((wv >> 1) << 11) + ((wv & 1) << 10);
    gl_lds16(aBase + (size_t)(m0 + aRow) * Dd + k + koff, aDst);
    // W: wave w stages rows [WR*w, WR*w+WR), WR=64 wide / 32 narrow.
    constexpr int WR = WIDE ? 64 : 32;
    const u16* wSrc = W + (size_t)(n0 + WR * wv + srow) * Dd + k + koff;
    char* wDst = buf + 4096 + wv * (WIDE ? 4096 : 2048);
    #pragma unroll
    for (int c = 0; c < (WIDE ? 4 : 2); ++c)
        gl_lds16(wSrc + (size_t)(16 * c) * Dd, wDst + (c << 10));
}

template<int MODE, bool WIDE>
__device__ inline void run_gemm(const u16* aH0, const u16* aL0, const u16* W0p,
                                const u16* aH1, const u16* aL1, const u16* W1p,
                                const int npass, const int m0, const int n0, char* smem,
                                const float* bias, const float* add,
                                const float* pF, const u16* pH, const u16* pL,
                                float* outF, u16* oH, u16* oL, const long zOff)
{
    const int lane = threadIdx.x & 63, wv = threadIdx.x >> 6;
    constexpr int NJ = WIDE ? 4 : 2;     // n-frags per wave (wave tile 32 x 16*NJ)
    f32x4 acc[2][NJ] = {};
    const int nk = npass << 7;           // 128 K-tiles per pass

    // Prologue: prefetch tiles 0,1 (2G outstanding; nk >= 128 so both are pass 0).
    stage_tile<WIDE>(aH0, aL0, W0p, m0, n0, 0,  smem,        wv, lane);
    stage_tile<WIDE>(aH0, aL0, W0p, m0, n0, 32, smem + BUFB, wv, lane);

    int ib = 0;
    const int r16 = lane & 15;
    const int qoff = (((lane >> 4) ^ ((r16 >> 1) & 3)) << 4);   // swizzled read chunk (bytes)

    for (int kk = 0; kk < nk; ++kk) {
        // Wait for tile kk only (oldest G loads); tile kk+1 stays in flight.
        if (kk + 1 < nk) {
            if (WIDE) asm volatile("s_waitcnt vmcnt(5)" ::: "memory");
            else      asm volatile("s_waitcnt vmcnt(3)" ::: "memory");
        } else {
            asm volatile("s_waitcnt vmcnt(0)" ::: "memory");
        }
        __builtin_amdgcn_s_barrier();
        asm volatile("" ::: "memory");   // keep ds_reads below the barrier

        // Prefetch tile kk+2 into buffer (ib+2)%3 == buffer read at iter kk-1:
        // all waves passed this barrier => all finished reading it. Race-free with
        // a single barrier per iteration.
        const int kk2 = kk + 2;
        if (kk2 < nk) {
            int ib2 = ib + 2; if (ib2 >= NBUF) ib2 -= NBUF;
            const bool p1 = kk2 >= 128;
            stage_tile<WIDE>(p1 ? aH1 : aH0, p1 ? aL1 : aL0, p1 ? W1p : W0p,
                             m0, n0, (kk2 & 127) << 5, smem + ib2 * BUFB, wv, lane);
        }

        const char* buf = smem + ib * BUFB;
        ++ib; if (ib == NBUF) ib = 0;

        f16x8 ah[2], al[2], wf[NJ];
        #pragma unroll
        for (int i = 0; i < 2; ++i) {
            ah[i] = *(const f16x8*)(buf + ((16 * i + r16) << 6) + qoff);
            al[i] = *(const f16x8*)(buf + 2048 + ((16 * i + r16) << 6) + qoff);
        }
        #pragma unroll
        for (int j = 0; j < NJ; ++j)
            wf[j] = *(const f16x8*)(buf + 4096 +
                        (((WIDE ? 64 : 32) * wv + 16 * j + r16) << 6) + qoff);

        __builtin_amdgcn_s_setprio(1);
        #pragma unroll
        for (int j = 0; j < NJ; ++j) {
            #pragma unroll
            for (int i = 0; i < 2; ++i) {
                acc[i][j] = __builtin_amdgcn_mfma_f32_16x16x32_f16(ah[i], wf[j], acc[i][j], 0, 0, 0);
                acc[i][j] = __builtin_amdgcn_mfma_f32_16x16x32_f16(al[i], wf[j], acc[i][j], 0, 0, 0);
            }
        }
        __builtin_amdgcn_s_setprio(0);
    }

    // Epilogue. C/D layout: row m = (lane>>4)*4 + reg, col n = lane&15.
    const int q = lane >> 4;
    #pragma unroll
    for (int j = 0; j < NJ; ++j) {
        const int n = n0 + (WIDE ? 64 : 32) * wv + 16 * j + r16;
        #pragma unroll
        for (int i = 0; i < 2; ++i) {
            #pragma unroll
            for (int r = 0; r < 4; ++r) {
                const int m = m0 + 16 * i + q * 4 + r;
                const size_t idx = (size_t)m * Dd + n;
                float e = acc[i][j][r];
                if (MODE == 0) {
                    outF[idx] = e + bias[n];
                } else {
                    if (bias) e += bias[n];
                    if (add)  e += add[idx];
                    const float p = pF ? pF[zOff + idx] : (h2f(pH[zOff + idx]) + h2f(pL[zOff + idx]));
                    float v = 0.5f * p + 0.5f * e;
                    v = fminf(fmaxf(v, 0.f), 1.f);
                    const u16 hb = f2h(v);
                    oH[zOff + idx] = hb;
                    oL[zOff + idx] = f2h(v - h2f(hb));
                    if (outF) outF[zOff + idx] = v;
                }
            }
        }
    }
}

// MODE 0: top = rho(s3)@W4^T + b4. Grid 256 narrow blocks (BN=128); W4h/b4 arrive in
//         the W0h/b0 slots.
// MODE 1: fused step, grid 512: [0,128) z0 wide | [128,384) z1 narrow 2-pass | [384,512) z2 wide.
//         n-major decode with n-stride ≡ 0 (mod 8) so same-W blocks land on one XCD.
template<int MODE>
__global__ __launch_bounds__(256, 2)
void step_mfma(const u16* __restrict__ sH, const u16* __restrict__ sL,
               const u16* __restrict__ W0h, const u16* __restrict__ W1h,
               const u16* __restrict__ W2h, const u16* __restrict__ W3h,
               const float* __restrict__ b0, const float* __restrict__ b2,
               const float* __restrict__ top,
               const float* __restrict__ pF,
               const u16* __restrict__ pH, const u16* __restrict__ pL,
               float* __restrict__ outF,
               u16* __restrict__ oH, u16* __restrict__ oL)
{
    __shared__ __align__(16) char smem[NBUF * BUFB];   // 60 KB -> 2 blocks/CU
    const int id = blockIdx.x;

    if (MODE == 0) {
        const int mt = id >> 5, nt = id & 31;
        run_gemm<0, false>(sH, sL, W0h, nullptr, nullptr, nullptr, 1,
                           mt * BM, nt * 128, smem, b0, nullptr,
                           nullptr, nullptr, nullptr, outF, nullptr, nullptr, 0);
    } else {
        if (id < 128) {              // z0: r1@W0^T + b0
            const int mt = id >> 4, nt = id & 15;
            run_gemm<1, true>(sH + BD, sL + BD, W0h, nullptr, nullptr, nullptr, 1,
                              mt * BM, nt * 256, smem, b0, nullptr,
                              pF, pH, pL, outF, oH, oL, 0);
        } else if (id < 384) {       // z1: r2@W2^T (pass 0) + r0@W1^T (pass 1) + b2
            const int t = id - 128, mt = t >> 5, nt = t & 31;
            run_gemm<1, false>(sH + 2 * BD, sL + 2 * BD, W2h, sH, sL, W1h, 2,
                               mt * BM, nt * 128, smem, b2, nullptr,
                               pF, pH, pL, outF, oH, oL, BD);
        } else {                     // z2: top + r1@W3^T
            const int t = id - 384, mt = t >> 4, nt = t & 15;
            run_gemm<1, true>(sH + BD, sL + BD, W3h, nullptr, nullptr, nullptr, 1,
                              mt * BM, nt * 256, smem, nullptr, top,
                              pF, pH, pL, outF, oH, oL, 2 * BD);
        }
    }
}

extern "C" void kernel_launch(void* const* d_in, const int* in_sizes, int n_in,
                              void* d_out, int out_size, void* d_ws, size_t ws_size,
                              hipStream_t stream)
{
    const float* s0 = (const float*)d_in[0];
    const float* s1 = (const float*)d_in[1];
    const float* s2 = (const float*)d_in[2];
    const float* s3 = (const float*)d_in[3];
    const float* W0 = (const float*)d_in[4];
    const float* b0 = (const float*)d_in[5];
    const float* W1 = (const float*)d_in[6];
    const float* W2 = (const float*)d_in[7];
    const float* b2 = (const float*)d_in[8];
    const float* W3 = (const float*)d_in[9];
    const float* W4 = (const float*)d_in[10];
    const float* b4 = (const float*)d_in[11];

    float* top = (float*)d_ws;                      // BD fp32 = 4 MB
    u16* u   = (u16*)(top + BD);
    u16* W0h = u;            u16* W1h = u + DD;     u16* W2h = u + 2 * DD;
    u16* W3h = u + 3 * DD;   u16* W4h = u + 4 * DD; // 160 MB
    u16* sHa = u + 5 * DD;      // 3*BD hi ping
    u16* sLa = sHa + 3 * BD;    // 3*BD lo ping
    u16* sHb = sLa + 3 * BD;    // 3*BD hi pong
    u16* sLb = sHb + 3 * BD;    // 3*BD lo pong
    u16* s3h = sLb + 3 * BD;
    u16* s3l = s3h + BD;

    float* out = (float*)d_out;
    const dim3 blk(256);
    const dim3 cgrid(512);

    convert_w<<<cgrid, blk, 0, stream>>>(W0, W0h, DD);
    convert_w<<<cgrid, blk, 0, stream>>>(W1, W1h, DD);
    convert_w<<<cgrid, blk, 0, stream>>>(W2, W2h, DD);
    convert_w<<<cgrid, blk, 0, stream>>>(W3, W3h, DD);
    convert_w<<<cgrid, blk, 0, stream>>>(W4, W4h, DD);
    convert_s<<<cgrid, blk, 0, stream>>>(s3, s3h, s3l, BD);
    convert_s<<<cgrid, blk, 0, stream>>>(s0, sHa,          sLa,          BD);
    convert_s<<<cgrid, blk, 0, stream>>>(s1, sHa + BD,     sLa + BD,     BD);
    convert_s<<<cgrid, blk, 0, stream>>>(s2, sHa + 2 * BD, sLa + 2 * BD, BD);

    // top = rho(s3) @ W4^T + b4
    step_mfma<0><<<dim3(256), blk, 0, stream>>>(
        s3h, s3l, W4h, nullptr, nullptr, nullptr,
        b4, nullptr, nullptr,
        nullptr, nullptr, nullptr,
        top, nullptr, nullptr);

    for (int t = 0; t < NSTEPS; ++t) {
        const u16* iH = (t & 1) ? sHb : sHa;
        const u16* iL = (t & 1) ? sLb : sLa;
        u16*       vH = (t & 1) ? sHa : sHb;
        u16*       vL = (t & 1) ? sLa : sLb;
        float* oF = (t == NSTEPS - 1) ? out : nullptr;
        if (t == 0) {
            // prev must be the raw fp32 inputs; stage them contiguously in d_out
            hipMemcpyAsync(out,          s0, BD * sizeof(float), hipMemcpyDeviceToDevice, stream);
            hipMemcpyAsync(out + BD,     s1, BD * sizeof(float), hipMemcpyDeviceToDevice, stream);
            hipMemcpyAsync(out + 2 * BD, s2, BD * sizeof(float), hipMemcpyDeviceToDevice, stream);
            step_mfma<1><<<dim3(512), blk, 0, stream>>>(
                iH, iL, W0h, W1h, W2h, W3h, b0, b2, top,
                out, nullptr, nullptr,
                oF, vH, vL);
        } else {
            step_mfma<1><<<dim3(512), blk, 0, stream>>>(
                iH, iL, W0h, W1h, W2h, W3h, b0, b2, top,
                nullptr, iH, iL,
                oF, vH, vL);
        }
    }
}

// Round 4
// 3757.512 us; speedup vs baseline: 1.2660x; 1.0006x over previous
//
#include <hip/hip_runtime.h>

// EP free-phase relaxation — fp16 MFMA, 2-term activation split, deep-pipelined K-loop.
// B=256, D=4096, N=30, DT=0.5.
//   n0 = clip(0.5*c0 + 0.5*(r1@W0^T + b0))
//   n1 = clip(0.5*c1 + 0.5*(r2@W2^T + r0@W1^T + b2))
//   n2 = clip(0.5*c2 + 0.5*(top + r1@W3^T))            top = r3@W4^T + b4
// Numerics: W fp16; activations split hi+lo fp16, both into one fp32 MFMA
// accumulator (absmax 7.8e-3). Layer-1 split-K: two fp32 partials summed in
// a finish kernel (fp32 add is order-independent -> same numerics class).
//
// R4 = R3 resubmitted byte-identical (R2/R3 failures diagnosed as infra: R1's
// timing showed push_in_npz_s=2599s on the same node; full bounds re-audit of
// R3 found no OOB/hang candidate; ws footprint == R1's verified 192 MB).
//
// Structure: UNIFORM blocks (load balance fix).
//  - All GEMM blocks identical: BM=32, BN=256, BK=32, 128 K-iters, 16 MFMA/wave/iter.
//  - Grid 512: [0,128) z0 | [128,256) z1a: r2@W2^T+b2 -> p0 | [256,384) z1b:
//    r0@W1^T -> p1 | [384,512) z2. Exactly 2 blocks/CU, identical work everywhere.
//  - finish_l1: n1 = clip(0.5*prev + 0.5*(p0+p1)), hi/lo re-split. ~12MB traffic.
//  - Pipeline: 3 rotating LDS buffers (60KB), prefetch depth 2, ONE s_barrier/iter,
//    counted s_waitcnt vmcnt(5) (never 0 in steady state).
//  - LDS 16B-chunk XOR swizzle on global src + ds_read offset (0 bank conflicts, R1).
//  - s_setprio(1) around MFMA cluster.

typedef unsigned short u16;
typedef __attribute__((ext_vector_type(8))) _Float16 f16x8;
typedef __attribute__((ext_vector_type(4))) float f32x4;

constexpr int Bb = 256, Dd = 4096, NSTEPS = 30;
constexpr long BD = (long)Bb * Dd;   // 1,048,576
constexpr long DD = (long)Dd * Dd;   // 16,777,216
constexpr int BM = 32;
constexpr int NBUF = 3;
constexpr int BUFB = 20480;          // per-buffer: AsH 2K | AsL 2K | Ws 16K

__device__ inline u16 f2h(float f) { union { _Float16 h; u16 u; } v; v.h = (_Float16)f; return v.u; }
__device__ inline float h2f(u16 b) { union { u16 u; _Float16 h; } v; v.u = b; return (float)v.h; }

__device__ inline void gl_lds16(const u16* g, void* l) {
    __builtin_amdgcn_global_load_lds(
        (const __attribute__((address_space(1))) void*)g,
        (__attribute__((address_space(3))) void*)l, 16, 0, 0);
}

__global__ __launch_bounds__(256)
void convert_w(const float* __restrict__ src, u16* __restrict__ dst, long n) {
    long i = (long)blockIdx.x * blockDim.x + threadIdx.x;
    const long stride = (long)gridDim.x * blockDim.x;
    for (long v = i; v < (n >> 2); v += stride) {
        float4 x = ((const float4*)src)[v];
        ushort4 o; o.x = f2h(x.x); o.y = f2h(x.y); o.z = f2h(x.z); o.w = f2h(x.w);
        ((ushort4*)dst)[v] = o;
    }
}

__global__ __launch_bounds__(256)
void convert_s(const float* __restrict__ src, u16* __restrict__ hi, u16* __restrict__ lo, long n) {
    long i = (long)blockIdx.x * blockDim.x + threadIdx.x;
    const long stride = (long)gridDim.x * blockDim.x;
    for (long v = i; v < (n >> 2); v += stride) {
        float4 x = ((const float4*)src)[v];
        float a[4] = {x.x, x.y, x.z, x.w};
        ushort4 oh, ol;
        u16* ph = (u16*)&oh; u16* pl = (u16*)&ol;
        #pragma unroll
        for (int j = 0; j < 4; ++j) {
            float c = fminf(fmaxf(a[j], 0.f), 1.f);
            u16 hb = f2h(c);
            ph[j] = hb;
            pl[j] = f2h(c - h2f(hb));
        }
        ((ushort4*)hi)[v] = oh;
        ((ushort4*)lo)[v] = ol;
    }
}

// Stage one BK=32 K-tile (BN=256) into LDS buffer `buf`.
// Layout: AsH [32][32] @0 | AsL @2048 | Ws [256][32] @4096. 64B rows, linear
// gl_lds dest (waveBase + lane*16); slot c of row r holds global chunk
// c ^ ((r%16)>>1 & 3) via the swizzled GLOBAL source address.
__device__ inline void stage_tile(const u16* aH, const u16* aL, const u16* W,
                                  int m0, int n0, int k, char* buf, int wv, int lane)
{
    const int srow = lane >> 2;
    const int koff = (((lane & 3) ^ ((lane >> 3) & 3)) << 3);    // swizzled chunk (elements)
    // A: waves 0/1 stage hi rows [16w,16w+16); waves 2/3 stage lo.
    const u16* aBase = (wv < 2) ? aH : aL;
    const int aRow = ((wv & 1) << 4) + srow;
    char* aDst = buf + ((wv >> 1) << 11) + ((wv & 1) << 10);
    gl_lds16(aBase + (size_t)(m0 + aRow) * Dd + k + koff, aDst);
    // W: wave w stages rows [64w, 64w+64).
    const u16* wSrc = W + (size_t)(n0 + 64 * wv + srow) * Dd + k + koff;
    char* wDst = buf + 4096 + wv * 4096;
    #pragma unroll
    for (int c = 0; c < 4; ++c)
        gl_lds16(wSrc + (size_t)(16 * c) * Dd, wDst + (c << 10));
}

// FULL=false: outF[idx] = acc (+bias)           (top and split-K partials)
// FULL=true : full step epilogue (prev merge, clip, hi/lo split)
template<bool FULL>
__device__ inline void run_gemm(const u16* aH, const u16* aL, const u16* W,
                                const int m0, const int n0, char* smem,
                                const float* bias, const float* add,
                                const float* pF, const u16* pH, const u16* pL,
                                float* outF, u16* oH, u16* oL, const long zOff)
{
    const int lane = threadIdx.x & 63, wv = threadIdx.x >> 6;
    f32x4 acc[2][4] = {};
    constexpr int nk = 128;

    // Prologue: prefetch tiles 0,1 (10 loads outstanding).
    stage_tile(aH, aL, W, m0, n0, 0,  smem,        wv, lane);
    stage_tile(aH, aL, W, m0, n0, 32, smem + BUFB, wv, lane);

    int ib = 0;
    const int r16 = lane & 15;
    const int qoff = (((lane >> 4) ^ ((r16 >> 1) & 3)) << 4);   // swizzled read chunk (bytes)

    for (int kk = 0; kk < nk; ++kk) {
        // Wait for tile kk (oldest 5 loads); tile kk+1 stays in flight.
        if (kk + 1 < nk) asm volatile("s_waitcnt vmcnt(5)" ::: "memory");
        else             asm volatile("s_waitcnt vmcnt(0)" ::: "memory");
        __builtin_amdgcn_s_barrier();
        asm volatile("" ::: "memory");   // keep ds_reads below the barrier

        // Prefetch tile kk+2 into buffer (ib+2)%3 — last read at iter kk-1,
        // all waves have passed this barrier since. Race-free with one barrier.
        if (kk + 2 < nk) {
            int ib2 = ib + 2; if (ib2 >= NBUF) ib2 -= NBUF;
            stage_tile(aH, aL, W, m0, n0, (kk + 2) << 5, smem + ib2 * BUFB, wv, lane);
        }

        const char* buf = smem + ib * BUFB;
        ++ib; if (ib == NBUF) ib = 0;

        f16x8 ah[2], al[2], wf[4];
        #pragma unroll
        for (int i = 0; i < 2; ++i) {
            ah[i] = *(const f16x8*)(buf + ((16 * i + r16) << 6) + qoff);
            al[i] = *(const f16x8*)(buf + 2048 + ((16 * i + r16) << 6) + qoff);
        }
        #pragma unroll
        for (int j = 0; j < 4; ++j)
            wf[j] = *(const f16x8*)(buf + 4096 + ((64 * wv + 16 * j + r16) << 6) + qoff);

        __builtin_amdgcn_s_setprio(1);
        #pragma unroll
        for (int j = 0; j < 4; ++j) {
            #pragma unroll
            for (int i = 0; i < 2; ++i) {
                acc[i][j] = __builtin_amdgcn_mfma_f32_16x16x32_f16(ah[i], wf[j], acc[i][j], 0, 0, 0);
                acc[i][j] = __builtin_amdgcn_mfma_f32_16x16x32_f16(al[i], wf[j], acc[i][j], 0, 0, 0);
            }
        }
        __builtin_amdgcn_s_setprio(0);
    }

    // Epilogue. C/D layout: row m = (lane>>4)*4 + reg, col n = lane&15.
    const int q = lane >> 4;
    #pragma unroll
    for (int j = 0; j < 4; ++j) {
        const int n = n0 + 64 * wv + 16 * j + r16;
        #pragma unroll
        for (int i = 0; i < 2; ++i) {
            #pragma unroll
            for (int r = 0; r < 4; ++r) {
                const int m = m0 + 16 * i + q * 4 + r;
                const size_t idx = (size_t)m * Dd + n;
                float e = acc[i][j][r];
                if (!FULL) {
                    outF[idx] = bias ? e + bias[n] : e;
                } else {
                    if (bias) e += bias[n];
                    if (add)  e += add[idx];
                    const float p = pF ? pF[zOff + idx] : (h2f(pH[zOff + idx]) + h2f(pL[zOff + idx]));
                    float v = 0.5f * p + 0.5f * e;
                    v = fminf(fmaxf(v, 0.f), 1.f);
                    const u16 hb = f2h(v);
                    oH[zOff + idx] = hb;
                    oL[zOff + idx] = f2h(v - h2f(hb));
                    if (outF) outF[zOff + idx] = v;
                }
            }
        }
    }
}

// MODE 0: top = rho(s3)@W4^T + b4, grid 128 (W4h/b4 in W0h/b0 slots).
// MODE 1: fused step, grid 512 uniform:
//   [0,128)   z0 : full epi, A=r1, W0, b0, zOff 0
//   [128,256) z1a: partial p0 = r2@W2^T + b2
//   [256,384) z1b: partial p1 = r0@W1^T
//   [384,512) z2 : full epi, A=r1, W3, add=top, zOff 2BD
template<int MODE>
__global__ __launch_bounds__(256, 2)
void step_mfma(const u16* __restrict__ sH, const u16* __restrict__ sL,
               const u16* __restrict__ W0h, const u16* __restrict__ W1h,
               const u16* __restrict__ W2h, const u16* __restrict__ W3h,
               const float* __restrict__ b0, const float* __restrict__ b2,
               const float* __restrict__ top,
               const float* __restrict__ pF,
               const u16* __restrict__ pH, const u16* __restrict__ pL,
               float* __restrict__ outF,
               u16* __restrict__ oH, u16* __restrict__ oL,
               float* __restrict__ p0, float* __restrict__ p1)
{
    __shared__ __align__(16) char smem[NBUF * BUFB];   // 60 KB -> 2 blocks/CU
    const int id = blockIdx.x;

    if (MODE == 0) {
        const int mt = id >> 4, nt = id & 15;
        run_gemm<false>(sH, sL, W0h, mt * BM, nt * 256, smem, b0, nullptr,
                        nullptr, nullptr, nullptr, outF, nullptr, nullptr, 0);
    } else {
        const int t = id & 127, mt = t >> 4, nt = t & 15;
        const int m0 = mt * BM, n0 = nt * 256;
        if (id < 128) {              // z0
            run_gemm<true>(sH + BD, sL + BD, W0h, m0, n0, smem, b0, nullptr,
                           pF, pH, pL, outF, oH, oL, 0);
        } else if (id < 256) {       // z1a -> p0
            run_gemm<false>(sH + 2 * BD, sL + 2 * BD, W2h, m0, n0, smem, b2, nullptr,
                            nullptr, nullptr, nullptr, p0, nullptr, nullptr, 0);
        } else if (id < 384) {       // z1b -> p1
            run_gemm<false>(sH, sL, W1h, m0, n0, smem, nullptr, nullptr,
                            nullptr, nullptr, nullptr, p1, nullptr, nullptr, 0);
        } else {                     // z2
            run_gemm<true>(sH + BD, sL + BD, W3h, m0, n0, smem, nullptr, top,
                           pF, pH, pL, outF, oH, oL, 2 * BD);
        }
    }
}

// n1 = clip(0.5*prev1 + 0.5*(p0+p1)); hi/lo split; optional fp32 out (last step).
__global__ __launch_bounds__(256)
void finish_l1(const float* __restrict__ p0, const float* __restrict__ p1,
               const float* __restrict__ pF,
               const u16* __restrict__ pH, const u16* __restrict__ pL,
               float* __restrict__ outF, u16* __restrict__ oH, u16* __restrict__ oL)
{
    const long v = (long)blockIdx.x * blockDim.x + threadIdx.x;   // float4 index, BD/4 total
    float4 a = ((const float4*)p0)[v];
    float4 b = ((const float4*)p1)[v];
    float e[4] = {a.x + b.x, a.y + b.y, a.z + b.z, a.w + b.w};
    float p[4];
    if (pF) {
        float4 pv = ((const float4*)(pF + BD))[v];
        p[0] = pv.x; p[1] = pv.y; p[2] = pv.z; p[3] = pv.w;
    } else {
        ushort4 hv = ((const ushort4*)(pH + BD))[v];
        ushort4 lv = ((const ushort4*)(pL + BD))[v];
        p[0] = h2f(hv.x) + h2f(lv.x); p[1] = h2f(hv.y) + h2f(lv.y);
        p[2] = h2f(hv.z) + h2f(lv.z); p[3] = h2f(hv.w) + h2f(lv.w);
    }
    ushort4 oh, ol; u16* ph = (u16*)&oh; u16* pl = (u16*)&ol;
    float4 ov;
    float* po = (float*)&ov;
    #pragma unroll
    for (int j = 0; j < 4; ++j) {
        float x = 0.5f * p[j] + 0.5f * e[j];
        x = fminf(fmaxf(x, 0.f), 1.f);
        const u16 hb = f2h(x);
        ph[j] = hb;
        pl[j] = f2h(x - h2f(hb));
        po[j] = x;
    }
    ((ushort4*)(oH + BD))[v] = oh;
    ((ushort4*)(oL + BD))[v] = ol;
    if (outF) ((float4*)(outF + BD))[v] = ov;
}

extern "C" void kernel_launch(void* const* d_in, const int* in_sizes, int n_in,
                              void* d_out, int out_size, void* d_ws, size_t ws_size,
                              hipStream_t stream)
{
    const float* s0 = (const float*)d_in[0];
    const float* s1 = (const float*)d_in[1];
    const float* s2 = (const float*)d_in[2];
    const float* s3 = (const float*)d_in[3];
    const float* W0 = (const float*)d_in[4];
    const float* b0 = (const float*)d_in[5];
    const float* W1 = (const float*)d_in[6];
    const float* W2 = (const float*)d_in[7];
    const float* b2 = (const float*)d_in[8];
    const float* W3 = (const float*)d_in[9];
    const float* W4 = (const float*)d_in[10];
    const float* b4 = (const float*)d_in[11];

    float* top = (float*)d_ws;                      // BD fp32 = 4 MB
    u16* u   = (u16*)(top + BD);
    u16* W0h = u;            u16* W1h = u + DD;     u16* W2h = u + 2 * DD;
    u16* W3h = u + 3 * DD;   u16* W4h = u + 4 * DD; // 160 MB total for weights
    u16* sHa = u + 5 * DD;      // 3*BD hi ping
    u16* sLa = sHa + 3 * BD;    // 3*BD lo ping
    u16* sHb = sLa + 3 * BD;    // 3*BD hi pong
    u16* sLb = sHb + 3 * BD;    // 3*BD lo pong
    u16* s3h = sLb + 3 * BD;
    u16* s3l = s3h + BD;
    // Split-K partials ALIAS the W4h region (32 MB): W4h is consumed only by the
    // MODE0 "top" kernel, which is stream-ordered before every step_mfma<1>.
    // Keeps total workspace at the previously-verified 192 MB.
    float* p0 = (float*)W4h;          // BD fp32 (4 MB)
    float* p1 = p0 + BD;              // BD fp32 (4 MB)

    float* out = (float*)d_out;
    const dim3 blk(256);
    const dim3 cgrid(512);

    convert_w<<<cgrid, blk, 0, stream>>>(W0, W0h, DD);
    convert_w<<<cgrid, blk, 0, stream>>>(W1, W1h, DD);
    convert_w<<<cgrid, blk, 0, stream>>>(W2, W2h, DD);
    convert_w<<<cgrid, blk, 0, stream>>>(W3, W3h, DD);
    convert_w<<<cgrid, blk, 0, stream>>>(W4, W4h, DD);
    convert_s<<<cgrid, blk, 0, stream>>>(s3, s3h, s3l, BD);
    convert_s<<<cgrid, blk, 0, stream>>>(s0, sHa,          sLa,          BD);
    convert_s<<<cgrid, blk, 0, stream>>>(s1, sHa + BD,     sLa + BD,     BD);
    convert_s<<<cgrid, blk, 0, stream>>>(s2, sHa + 2 * BD, sLa + 2 * BD, BD);

    // top = rho(s3) @ W4^T + b4   (last use of W4h; p0/p1 overwrite it afterwards)
    step_mfma<0><<<dim3(128), blk, 0, stream>>>(
        s3h, s3l, W4h, nullptr, nullptr, nullptr,
        b4, nullptr, nullptr,
        nullptr, nullptr, nullptr,
        top, nullptr, nullptr, nullptr, nullptr);

    for (int t = 0; t < NSTEPS; ++t) {
        const u16* iH = (t & 1) ? sHb : sHa;
        const u16* iL = (t & 1) ? sLb : sLa;
        u16*       vH = (t & 1) ? sHa : sHb;
        u16*       vL = (t & 1) ? sLa : sLb;
        float* oF = (t == NSTEPS - 1) ? out : nullptr;
        const float* pF = nullptr;
        if (t == 0) {
            // prev must be the raw fp32 inputs; stage them contiguously in d_out
            hipMemcpyAsync(out,          s0, BD * sizeof(float), hipMemcpyDeviceToDevice, stream);
            hipMemcpyAsync(out + BD,     s1, BD * sizeof(float), hipMemcpyDeviceToDevice, stream);
            hipMemcpyAsync(out + 2 * BD, s2, BD * sizeof(float), hipMemcpyDeviceToDevice, stream);
            pF = out;
        }
        step_mfma<1><<<dim3(512), blk, 0, stream>>>(
            iH, iL, W0h, W1h, W2h, W3h, b0, b2, top,
            pF, iH, iL,
            oF, vH, vL, p0, p1);
        finish_l1<<<dim3(BD / 4 / 256), blk, 0, stream>>>(
            p0, p1, pF, iH, iL, oF, vH, vL);
    }
}